// Round 7
// baseline (39.857 us; speedup 1.0000x reference)
//
#include <hip/hip_runtime.h>
#include <math.h>

// Problem constants
#define Dq 512
#define Vq 50257
#define Kq 100
#define NORM_TERM 10.8249051f   // log(50257)
#define LOGK 4.6051702f         // log(100)
#define NBLK 1024           // 16384 positions / 16 per block

typedef __attribute__((ext_vector_type(8))) short short8;
typedef __attribute__((ext_vector_type(4))) float floatx4;
typedef __attribute__((ext_vector_type(8))) unsigned short ushort8v;

__device__ __forceinline__ unsigned short f2bf(float f) {
    union { float f; unsigned u; } v; v.f = f;
    unsigned r = v.u + 0x7FFFu + ((v.u >> 16) & 1u);   // RNE
    return (unsigned short)(r >> 16);
}

__device__ __forceinline__ short8 cvt8(floatx4 a, floatx4 b) {
    short8 o;
    o[0] = (short)f2bf(a.x); o[1] = (short)f2bf(a.y);
    o[2] = (short)f2bf(a.z); o[3] = (short)f2bf(a.w);
    o[4] = (short)f2bf(b.x); o[5] = (short)f2bf(b.y);
    o[6] = (short)f2bf(b.z); o[7] = (short)f2bf(b.w);
    return o;
}

__device__ __forceinline__ float log_sigmoid(float x) {
    return fminf(x, 0.f) - __logf(1.f + __expf(-fabsf(x)));
}

// Single main kernel (no prep): block = 4 waves = 16 positions.
// Stage 16 input rows once to LDS bf16 (XOR-swizzled); ONE barrier.
// Wave w<3: noise k-tiles {2w,2w+1}, rows gathered fp32 from emb_weight
// (L2/L3-hot, 229 KB unique) + inline cvt -> MFMA. Wave 3: noise k-tile 6
// + target tile (diag in-register). All waves symmetric: 32 MFMAs, 64
// fp32x4 gather loads. Per-wave partial -> partials[bid*4+w].
__global__ __launch_bounds__(256, 4) void nce_main(
    const float* __restrict__ input,     // [16384][512]
    const float* __restrict__ emb_w,     // [V][512]
    const float* __restrict__ emb_b,     // [V]
    const float* __restrict__ lpn,       // [V]
    const int* __restrict__ target,      // [16384]
    const int* __restrict__ ns,          // [100]
    float* __restrict__ partials)        // [4096]
{
    __shared__ unsigned short A_lds[16 * 512];  // byte: row*1024 + (2c ^ ((row&7)<<4))

    int tid  = threadIdx.x;
    int lane = tid & 63;
    int w    = tid >> 6;            // 0..3
    int pos0 = (int)blockIdx.x * 16;
    int r16  = lane & 15;
    int g4   = lane >> 4;

    // ---- Stage 16 input rows -> LDS bf16 (each wave 4 rows, 32B/lane) ----
    {
        int row = w * 4 + g4;
        const float* src = input + (size_t)(pos0 + row) * Dq;
        char* base = (char*)A_lds + row * 1024;
        int sw = (row & 7) << 4;
#pragma unroll
        for (int j = 0; j < 4; ++j) {
            int c = r16 * 8 + j * 128;        // float col
            floatx4 x0 = *(const floatx4*)(src + c);
            floatx4 x1 = *(const floatx4*)(src + c + 4);
            *(ushort8v*)(base + ((c * 2) ^ sw)) = (ushort8v)cvt8(x0, x1);
        }
    }
    __syncthreads();

    const char* abase = (const char*)A_lds + r16 * 1024;
    int asw = (r16 & 7) << 4;

    float contrib = 0.f;

    if (w < 3) {
        // ---- Noise k-tiles 2w, 2w+1 (k = w*32+r16, +16; all < 96) ----
        int k0 = w * 32 + r16, k1 = k0 + 16;
        const float* n0 = emb_w + (size_t)ns[k0] * Dq + g4 * 8;
        const float* n1 = emb_w + (size_t)ns[k1] * Dq + g4 * 8;
        floatx4 acc0 = {0.f, 0.f, 0.f, 0.f};
        floatx4 acc1 = {0.f, 0.f, 0.f, 0.f};
#pragma unroll
        for (int dt = 0; dt < 16; ++dt) {
            short8 a = *(const short8*)(abase + ((dt * 64 + g4 * 16) ^ asw));
            floatx4 u0 = *(const floatx4*)(n0 + dt * 32);
            floatx4 u1 = *(const floatx4*)(n0 + dt * 32 + 4);
            floatx4 v0 = *(const floatx4*)(n1 + dt * 32);
            floatx4 v1 = *(const floatx4*)(n1 + dt * 32 + 4);
            acc0 = __builtin_amdgcn_mfma_f32_16x16x32_bf16(a, cvt8(u0, u1), acc0, 0, 0, 0);
            acc1 = __builtin_amdgcn_mfma_f32_16x16x32_bf16(a, cvt8(v0, v1), acc1, 0, 0, 0);
        }
        int row0 = ns[k0], row1 = ns[k1];
        float adj0 = emb_b[row0] - NORM_TERM - lpn[row0] - LOGK;
        float adj1 = emb_b[row1] - NORM_TERM - lpn[row1] - LOGK;
#pragma unroll
        for (int r = 0; r < 4; ++r) {
            contrib += log_sigmoid(-(acc0[r] + adj0));
            contrib += log_sigmoid(-(acc1[r] + adj1));
        }
    } else {
        // ---- Noise k-tile 6 (k=96..111, valid <100) + target tile ----
        int k6 = 96 + r16;
        int row6 = ns[k6 < Kq ? k6 : Kq - 1];      // clamp: garbage cols unread
        int tgt = target[pos0 + r16];
        const float* n6 = emb_w + (size_t)row6 * Dq + g4 * 8;
        const float* tr = emb_w + (size_t)tgt  * Dq + g4 * 8;
        floatx4 acc6 = {0.f, 0.f, 0.f, 0.f};
        floatx4 accT = {0.f, 0.f, 0.f, 0.f};
#pragma unroll
        for (int dt = 0; dt < 16; ++dt) {
            short8 a = *(const short8*)(abase + ((dt * 64 + g4 * 16) ^ asw));
            floatx4 u0 = *(const floatx4*)(n6 + dt * 32);
            floatx4 u1 = *(const floatx4*)(n6 + dt * 32 + 4);
            floatx4 v0 = *(const floatx4*)(tr + dt * 32);
            floatx4 v1 = *(const floatx4*)(tr + dt * 32 + 4);
            acc6 = __builtin_amdgcn_mfma_f32_16x16x32_bf16(a, cvt8(u0, u1), acc6, 0, 0, 0);
            accT = __builtin_amdgcn_mfma_f32_16x16x32_bf16(a, cvt8(v0, v1), accT, 0, 0, 0);
        }
        if (k6 < Kq) {
            float adj6 = emb_b[row6] - NORM_TERM - lpn[row6] - LOGK;
#pragma unroll
            for (int r = 0; r < 4; ++r)
                contrib += log_sigmoid(-(acc6[r] + adj6));
        }
        // D[row=g4*4+reg][col=r16]; diag of position r16 lives at g4==r16>>2
        if ((r16 >> 2) == g4) {
            float xt = accT[r16 & 3] + emb_b[tgt] - NORM_TERM - lpn[tgt] - LOGK;
            contrib += log_sigmoid(xt);
        }
    }

#pragma unroll
    for (int off = 32; off >= 1; off >>= 1)
        contrib += __shfl_xor(contrib, off);
    if (lane == 0) partials[(size_t)blockIdx.x * 4 + w] = contrib;
}

// Deterministic per-batch reduction: 64 batches x 64 partials each.
__global__ void finalize(const float* __restrict__ partials,
                         float* __restrict__ out) {
    __shared__ float s4[64][5];        // padded
    int t = threadIdx.x;               // 0..255
    int b = t >> 2, q = t & 3;
    float s = 0.f;
#pragma unroll
    for (int i = 0; i < 16; ++i) s += partials[b * 64 + q * 16 + i];
    s4[b][q] = s;
    __syncthreads();
    if (t < 64) out[t] = s4[t][0] + s4[t][1] + s4[t][2] + s4[t][3];
}

extern "C" void kernel_launch(void* const* d_in, const int* in_sizes, int n_in,
                              void* d_out, int out_size, void* d_ws, size_t ws_size,
                              hipStream_t stream) {
    const float* input = (const float*)d_in[0];
    const float* emb_w = (const float*)d_in[1];
    const float* emb_b = (const float*)d_in[2];
    const float* lpn   = (const float*)d_in[3];
    const int*   tgt   = (const int*)d_in[4];
    const int*   ns    = (const int*)d_in[5];
    float* out = (float*)d_out;

    float* partials = (float*)d_ws;    // 4096 floats

    nce_main<<<NBLK, 256, 0, stream>>>(input, emb_w, emb_b, lpn, tgt, ns,
                                       partials);
    finalize<<<1, 256, 0, stream>>>(partials, out);
}

// Round 8
// 27.891 us; speedup vs baseline: 1.4290x; 1.4290x over previous
//
#include <hip/hip_runtime.h>
#include <math.h>

// Problem constants
#define Dq 512
#define Vq 50257
#define Kq 100
#define KP 112              // K padded to 7*16
#define NORM_TERM 10.8249051f   // log(50257)
#define LOGK 4.6051702f         // log(100)
#define NBLK 1024           // 16384 positions / 16 per block
#define DT_STRIDE 3584      // KP*32 elements per d-chunk slab

typedef __attribute__((ext_vector_type(8))) short short8;
typedef __attribute__((ext_vector_type(4))) float floatx4;
typedef __attribute__((ext_vector_type(4))) unsigned short ushort4v;
typedef __attribute__((ext_vector_type(8))) unsigned short ushort8v;

__device__ __forceinline__ unsigned short f2bf(float f) {
    union { float f; unsigned u; } v; v.f = f;
    unsigned r = v.u + 0x7FFFu + ((v.u >> 16) & 1u);   // RNE
    return (unsigned short)(r >> 16);
}

__device__ __forceinline__ short8 cvt8(floatx4 a, floatx4 b) {
    short8 o;
    o[0] = (short)f2bf(a.x); o[1] = (short)f2bf(a.y);
    o[2] = (short)f2bf(a.z); o[3] = (short)f2bf(a.w);
    o[4] = (short)f2bf(b.x); o[5] = (short)f2bf(b.y);
    o[6] = (short)f2bf(b.z); o[7] = (short)f2bf(b.w);
    return o;
}

__device__ __forceinline__ float log_sigmoid(float x) {
    return fminf(x, 0.f) - __logf(1.f + __expf(-fabsf(x)));
}

// Gather + convert noise rows to bf16, TRANSPOSED chunk-major layout:
// element (k, d) at nBT[(d>>5)*DT_STRIDE + k*32 + (d&31)].
// => a wave reading 16 k-rows x 4 chunks of one dt hits ONE contiguous 1KB
// block (perfect coalescing / channel spread), instead of 1KB-strided lines.
__global__ void prep_noise(const float* __restrict__ emb_w,
                           const float* __restrict__ emb_b,
                           const float* __restrict__ lpn,
                           const int* __restrict__ ns,
                           unsigned short* __restrict__ nBT,
                           float* __restrict__ nAdj) {
    int k = blockIdx.x;     // 0..111
    int t = threadIdx.x;    // 0..127; d = t*4 .. t*4+3
    size_t off = (size_t)(t >> 3) * DT_STRIDE + k * 32 + (t & 7) * 4;
    if (k < Kq) {
        int row = ns[k];
        floatx4 v = ((const floatx4*)(emb_w + (size_t)row * Dq))[t];
        ushort4v o;
        o.x = f2bf(v.x); o.y = f2bf(v.y); o.z = f2bf(v.z); o.w = f2bf(v.w);
        *(ushort4v*)(nBT + off) = o;
        if (t == 0) nAdj[k] = emb_b[row] - NORM_TERM - lpn[row] - LOGK;
    } else {
        ushort4v z; z.x = 0; z.y = 0; z.z = 0; z.w = 0;
        *(ushort4v*)(nBT + off) = z;
        if (t == 0) nAdj[k] = 0.f;
    }
}

// Block = 4 waves = 16 positions. Stage 16 input rows once to LDS bf16
// (XOR-swizzled); ONE barrier. Wave w<3: noise k-tiles {2w,2w+1} from the
// transposed nBT (contiguous 1KB per wave-load). Wave 3: noise k-tile 6 +
// target tile full-D, diag in-register. Per-wave partials, no tail barriers.
__global__ __launch_bounds__(256, 4) void nce_main(
    const float* __restrict__ input,     // [16384][512]
    const float* __restrict__ emb_w,     // [V][512]
    const float* __restrict__ emb_b,     // [V]
    const float* __restrict__ lpn,       // [V]
    const int* __restrict__ target,      // [16384]
    const unsigned short* __restrict__ nBT,  // [16][112][32] bf16
    const float* __restrict__ nAdj,          // [112]
    float* __restrict__ partials)            // [4096]
{
    __shared__ unsigned short A_lds[16 * 512];  // byte: row*1024 + (2c ^ ((row&7)<<4))

    int tid  = threadIdx.x;
    int lane = tid & 63;
    int w    = tid >> 6;            // 0..3
    int pos0 = (int)blockIdx.x * 16;
    int r16  = lane & 15;
    int g4   = lane >> 4;

    // ---- Stage 16 input rows -> LDS bf16 (each wave 4 rows, 32B/lane) ----
    {
        int row = w * 4 + g4;
        const float* src = input + (size_t)(pos0 + row) * Dq;
        char* base = (char*)A_lds + row * 1024;
        int sw = (row & 7) << 4;
#pragma unroll
        for (int j = 0; j < 4; ++j) {
            int c = r16 * 8 + j * 128;        // float col
            floatx4 x0 = *(const floatx4*)(src + c);
            floatx4 x1 = *(const floatx4*)(src + c + 4);
            *(ushort8v*)(base + ((c * 2) ^ sw)) = (ushort8v)cvt8(x0, x1);
        }
    }
    __syncthreads();

    const char* abase = (const char*)A_lds + r16 * 1024;
    int asw = (r16 & 7) << 4;

    float contrib = 0.f;

    if (w < 3) {
        // ---- Noise k-tiles 2w, 2w+1: per dt, two contiguous 1KB bursts ----
        const unsigned short* p0 = nBT + (size_t)(2 * w) * 512 + r16 * 32 + g4 * 8;
        floatx4 acc0 = {0.f, 0.f, 0.f, 0.f};
        floatx4 acc1 = {0.f, 0.f, 0.f, 0.f};
#pragma unroll
        for (int dt = 0; dt < 16; ++dt) {
            short8 a  = *(const short8*)(abase + ((dt * 64 + g4 * 16) ^ asw));
            short8 f0 = *(const short8*)(p0 + (size_t)dt * DT_STRIDE);
            short8 f1 = *(const short8*)(p0 + (size_t)dt * DT_STRIDE + 512);
            acc0 = __builtin_amdgcn_mfma_f32_16x16x32_bf16(a, f0, acc0, 0, 0, 0);
            acc1 = __builtin_amdgcn_mfma_f32_16x16x32_bf16(a, f1, acc1, 0, 0, 0);
        }
        float adj0 = nAdj[w * 32 + r16];
        float adj1 = nAdj[w * 32 + 16 + r16];
#pragma unroll
        for (int r = 0; r < 4; ++r) {
            contrib += log_sigmoid(-(acc0[r] + adj0));
            contrib += log_sigmoid(-(acc1[r] + adj1));
        }
    } else {
        // ---- Noise k-tile 6 + target tile (full-D, diag in-register) ----
        int tgt = target[pos0 + r16];
        const unsigned short* p6 = nBT + (size_t)6 * 512 + r16 * 32 + g4 * 8;
        const float* tr = emb_w + (size_t)tgt * Dq + g4 * 8;
        floatx4 acc6 = {0.f, 0.f, 0.f, 0.f};
        floatx4 accT = {0.f, 0.f, 0.f, 0.f};
#pragma unroll
        for (int dt = 0; dt < 16; ++dt) {
            short8 a  = *(const short8*)(abase + ((dt * 64 + g4 * 16) ^ asw));
            short8 f6 = *(const short8*)(p6 + (size_t)dt * DT_STRIDE);
            floatx4 v0 = *(const floatx4*)(tr + dt * 32);
            floatx4 v1 = *(const floatx4*)(tr + dt * 32 + 4);
            acc6 = __builtin_amdgcn_mfma_f32_16x16x32_bf16(a, f6, acc6, 0, 0, 0);
            accT = __builtin_amdgcn_mfma_f32_16x16x32_bf16(a, cvt8(v0, v1), accT, 0, 0, 0);
        }
        if (96 + r16 < Kq) {
            float adj6 = nAdj[96 + r16];
#pragma unroll
            for (int r = 0; r < 4; ++r)
                contrib += log_sigmoid(-(acc6[r] + adj6));
        }
        // D[row=g4*4+reg][col=r16]; diag of position r16 lives at g4==r16>>2
        if ((r16 >> 2) == g4) {
            float xt = accT[r16 & 3] + emb_b[tgt] - NORM_TERM - lpn[tgt] - LOGK;
            contrib += log_sigmoid(xt);
        }
    }

#pragma unroll
    for (int off = 32; off >= 1; off >>= 1)
        contrib += __shfl_xor(contrib, off);
    if (lane == 0) partials[(size_t)blockIdx.x * 4 + w] = contrib;
}

// Deterministic per-batch reduction: 64 batches x 64 partials each.
__global__ void finalize(const float* __restrict__ partials,
                         float* __restrict__ out) {
    __shared__ float s4[64][5];        // padded
    int t = threadIdx.x;               // 0..255
    int b = t >> 2, q = t & 3;
    float s = 0.f;
#pragma unroll
    for (int i = 0; i < 16; ++i) s += partials[b * 64 + q * 16 + i];
    s4[b][q] = s;
    __syncthreads();
    if (t < 64) out[t] = s4[t][0] + s4[t][1] + s4[t][2] + s4[t][3];
}

extern "C" void kernel_launch(void* const* d_in, const int* in_sizes, int n_in,
                              void* d_out, int out_size, void* d_ws, size_t ws_size,
                              hipStream_t stream) {
    const float* input = (const float*)d_in[0];
    const float* emb_w = (const float*)d_in[1];
    const float* emb_b = (const float*)d_in[2];
    const float* lpn   = (const float*)d_in[3];
    const int*   tgt   = (const int*)d_in[4];
    const int*   ns    = (const int*)d_in[5];
    float* out = (float*)d_out;

    // ws layout: [0,114688) nBT bf16; [114688,115200) nAdj(+pad);
    // [115200,131584) partials[4096].
    unsigned short* nBT = (unsigned short*)d_ws;
    float* nAdj     = (float*)((char*)d_ws + (size_t)KP * Dq * 2);
    float* partials = (float*)((char*)d_ws + (size_t)KP * Dq * 2 + 512);

    prep_noise<<<KP, 128, 0, stream>>>(emb_w, emb_b, lpn, ns, nBT, nAdj);
    nce_main<<<NBLK, 256, 0, stream>>>(input, emb_w, emb_b, lpn, tgt, nBT, nAdj,
                                       partials);
    finalize<<<1, 256, 0, stream>>>(partials, out);
}